// Round 7
// baseline (646.428 us; speedup 1.0000x reference)
//
#include <hip/hip_runtime.h>

// ShiftedWindowAttention3d on MI355X (gfx950).
// x[1,16,56,56,192], WIN=(8,7,7), SHIFT=(4,3,3) -> no pad, shifted.
// 128 windows x 392 tokens, 6 heads x hd=32.
// Round 7: round-6 flash-style online softmax with the rescale-layout fix:
// m/s/sc are in A-frag layout (row=l15); oacc is in C/D layout (row=g*4+j);
// per-tile rescale must use __shfl(sc, g*4+j) per accumulator register.

typedef _Float16 f16;
typedef __attribute__((ext_vector_type(8))) _Float16 f16x8;
typedef __attribute__((ext_vector_type(4))) _Float16 f16x4;
typedef __attribute__((ext_vector_type(4))) float f32x4;
typedef __attribute__((ext_vector_type(4))) unsigned short u16x4;

#define MFMA_K32(a, b, c) __builtin_amdgcn_mfma_f32_16x16x32_f16((a), (b), (c), 0, 0, 0)
#define MFMA_K16(a, b, c) __builtin_amdgcn_mfma_f32_16x16x16f16((a), (b), (c), 0, 0, 0)
#define EXP2F(x) __builtin_amdgcn_exp2f(x)

#define HEADS 6
#define NWIN 128
#define NTOK 392
#define CDIM 192
#define TBLN 2535                    // 15*13*13
#define LOG2E 1.4426950408889634f
#define QSCALE 0.2550868562622215f    // hd^-0.5 * log2e
#define MASKF (-144.26950408889634f)  // -100 * log2e

__device__ inline f16x8 f16x8_zero() {
    f16x8 v = {(f16)0.f,(f16)0.f,(f16)0.f,(f16)0.f,(f16)0.f,(f16)0.f,(f16)0.f,(f16)0.f};
    return v;
}

// ---------------- kernel 0a: weights fp32 -> f16 (q rows pre-scaled) ----------------
__global__ __launch_bounds__(256) void wconv_kernel(
    const float* __restrict__ wqkv, const float* __restrict__ wproj,
    f16* __restrict__ wqkv_h, f16* __restrict__ wproj_h)
{
    int i = blockIdx.x * 256 + threadIdx.x;
    if (i < 576 * 192) {
        float s = (i < 192 * 192) ? QSCALE : 1.0f;
        wqkv_h[i] = (f16)(wqkv[i] * s);
    }
    if (i < 192 * 192) wproj_h[i] = (f16)wproj[i];
}

// ---------------- kernel 0b: per-head bias table transpose + colcode LUT ----------------
// tblT[head][2535] f16 = tbl[i*6+head] * log2e  (30.4 KB total)
// ccg[400] u16: for col m: (md*169+mh*13+mw) | (region_code << 12); 0 for m>=392.
__global__ __launch_bounds__(256) void tab_kernel(
    const float* __restrict__ tbl, f16* __restrict__ tblT,
    unsigned short* __restrict__ ccg)
{
    int i = blockIdx.x * 256 + threadIdx.x;
    if (i < HEADS * TBLN) {
        int h = i / TBLN, r = i - h * TBLN;
        tblT[i] = (f16)(tbl[r * 6 + h] * LOG2E);
    }
    if (i < 400) {
        unsigned short v = 0;
        if (i < NTOK) {
            int md = i / 49, m2 = i - md * 49, mh = m2 / 7, mw = m2 - mh * 7;
            int cc = md * 169 + mh * 13 + mw;
            int creg = ((md < 4) ? 4 : 0) | ((mh < 4) ? 2 : 0) | ((mw < 4) ? 1 : 0);
            v = (unsigned short)(cc | (creg << 12));
        }
        ccg[i] = v;
    }
}

// ---------------- kernel 1: gather(roll+window) + QKV GEMM ----------------
// grid 784: 64-token tile x all 576 outputs (two 288-halves). 256 threads.
__global__ __launch_bounds__(256, 3) void qkv_kernel(
    const float* __restrict__ x, const f16* __restrict__ wq,
    const float* __restrict__ bq,
    f16* __restrict__ q_ws, f16* __restrict__ k_ws, f16* __restrict__ v_ws)
{
    __shared__ __align__(16) f16 a_lds[64 * 256];  // 32 KB, swizzled
    const int tid = threadIdx.x;
    const int bm = blockIdx.x * 64;

    for (int i = tid; i < 64 * 24; i += 256) {
        int row = i / 24, c = i - row * 24;
        int tok = bm + row;
        int win = tok / NTOK, nloc = tok - win * NTOK;
        int td = nloc / 49, r2 = nloc - td * 49, th = r2 / 7, tw = r2 - th * 7;
        int wd = win >> 6, wh = (win >> 3) & 7, ww = win & 7;
        int d = (wd * 8 + td + 4) & 15;
        int hh = wh * 7 + th + 3; if (hh >= 56) hh -= 56;
        int wco = ww * 7 + tw + 3; if (wco >= 56) wco -= 56;
        const float* src = x + ((d * 56 + hh) * 56 + wco) * CDIM + c * 8;
        const float4 u0 = *(const float4*)(src);
        const float4 u1 = *(const float4*)(src + 4);
        f16x8 v;
        v[0] = (f16)u0.x; v[1] = (f16)u0.y; v[2] = (f16)u0.z; v[3] = (f16)u0.w;
        v[4] = (f16)u1.x; v[5] = (f16)u1.y; v[6] = (f16)u1.z; v[7] = (f16)u1.w;
        *(f16x8*)&a_lds[row * 256 + ((c ^ (row & 7)) << 3)] = v;
    }
    __syncthreads();

    const int lane = tid & 63, wv = tid >> 6;
    const int l15 = lane & 15, g = lane >> 4;
    const int m0 = (wv & 1) * 32, nq = wv >> 1;
    const f32x4 z4 = {0.f, 0.f, 0.f, 0.f};

    for (int half = 0; half < 2; half++) {
        const int n0 = half * 288 + nq * 144;
        f32x4 acc[2][9];
        #pragma unroll
        for (int mi = 0; mi < 2; mi++)
            #pragma unroll
            for (int ni = 0; ni < 9; ni++) acc[mi][ni] = z4;

        #pragma unroll
        for (int kk = 0; kk < 6; kk++) {
            f16x8 af[2];
            #pragma unroll
            for (int mi = 0; mi < 2; mi++) {
                int row = m0 + mi * 16 + l15;
                af[mi] = *(const f16x8*)&a_lds[row * 256 + (((kk * 4 + g) ^ (row & 7)) << 3)];
            }
            #pragma unroll
            for (int ni = 0; ni < 9; ni++) {
                const f16x8 bf = *(const f16x8*)&wq[(n0 + ni * 16 + l15) * CDIM + kk * 32 + g * 8];
                #pragma unroll
                for (int mi = 0; mi < 2; mi++)
                    acc[mi][ni] = MFMA_K32(af[mi], bf, acc[mi][ni]);
            }
        }

        #pragma unroll
        for (int mi = 0; mi < 2; mi++) {
            const int tok0 = bm + m0 + mi * 16 + g * 4;
            const int win = tok0 / NTOK, nloc0 = tok0 - win * NTOK;
            #pragma unroll
            for (int ni = 0; ni < 9; ni++) {
                const int n = n0 + ni * 16 + l15;
                const float bias = bq[n] * ((n < 192) ? QSCALE : 1.0f);
                if (n < 192) {
                    const int head = n >> 5, hd = n & 31;
                    f16* dst = q_ws + ((win * HEADS + head) * NTOK + nloc0) * 32 + hd;
                    #pragma unroll
                    for (int j = 0; j < 4; j++)
                        dst[j * 32] = (f16)(acc[mi][ni][j] + bias);
                } else if (n < 384) {
                    const int cc = n - 192, head = cc >> 5, hd = cc & 31;
                    f16* dst = k_ws + ((win * HEADS + head) * NTOK + nloc0) * 32 + hd;
                    #pragma unroll
                    for (int j = 0; j < 4; j++)
                        dst[j * 32] = (f16)(acc[mi][ni][j] + bias);
                } else {
                    const int cc = n - 384, head = cc >> 5, hd = cc & 31;
                    f16x4 pk;
                    #pragma unroll
                    for (int j = 0; j < 4; j++) pk[j] = (f16)(acc[mi][ni][j] + bias);
                    *(f16x4*)(v_ws + ((win * HEADS + head) * 32 + hd) * NTOK + nloc0) = pk;
                }
            }
        }
    }
}

// ---------------- kernel 2: fused window attention (swapped-S, online softmax) ----------------
// grid 768 = 128 win x 6 heads, 256 threads (4 waves), 2 blocks/CU.
__global__ __launch_bounds__(256, 2) void attn_kernel(
    const f16* __restrict__ q_ws, const f16* __restrict__ k_ws,
    const f16* __restrict__ v_ws, const f16* __restrict__ tblT,
    const unsigned short* __restrict__ ccg, f16* __restrict__ o_ws)
{
    __shared__ __align__(16) f16 k_lds[25 * 512];    // frag-major, 25.6 KB
    __shared__ __align__(16) f16 v_lds[32 * 408];    // V^T rows padded, 26.1 KB
    __shared__ __align__(16) f16 tbl_lds[TBLN + 1];  // per-head bias table, 5.1 KB
    __shared__ __align__(16) unsigned short cc_lds[400];  // colcode|creg<<12

    const int tid = threadIdx.x;
    const int bid = blockIdx.x;
    const int win = bid / 6, head = bid - win * 6;
    const int wd = win >> 6, wh = (win >> 3) & 7, ww = win & 7;
    const int wtype = ((wd == 1) ? 4 : 0) | ((wh == 7) ? 2 : 0) | ((ww == 7) ? 1 : 0);
    const f16* kb = k_ws + (size_t)(win * HEADS + head) * NTOK * 32;
    const f16* vb = v_ws + (size_t)(win * HEADS + head) * 32 * NTOK;
    const f16* qb = q_ws + (size_t)(win * HEADS + head) * NTOK * 32;

    // K frag-major: tile t, lane l -> K[t*16+(l&15)][(l>>4)*8..+8] at (t*64+l)*16B
    for (int i = tid; i < 1600; i += 256) {
        const int tok = ((i >> 6) << 4) | (i & 15);
        const int gg = (i >> 4) & 3;
        f16x8 v = f16x8_zero();
        if (tok < NTOK) v = *(const f16x8*)(kb + tok * 32 + gg * 8);
        *(f16x8*)&k_lds[i * 8] = v;
    }
    // V^T rows: v_lds[hd][tok], stride 408 (2-way bank alias = free)
    for (int i = tid; i < 32 * 51; i += 256) {
        const int hd = i / 51, c = i - hd * 51;
        f16x8 v = f16x8_zero();
        if (c < 49) v = *(const f16x8*)(vb + hd * NTOK + c * 8);
        *(f16x8*)&v_lds[hd * 408 + c * 8] = v;
    }
    // bias table slice + colcode LUT
    for (int i = tid; i < TBLN; i += 256) tbl_lds[i] = tblT[head * TBLN + i];
    for (int i = tid; i < 400; i += 256) cc_lds[i] = ccg[i];
    __syncthreads();

    const int lane = tid & 63, wv = tid >> 6, l15 = lane & 15, g = lane >> 4;
    const f32x4 z4 = {0.f, 0.f, 0.f, 0.f};

    for (int strip = wv; strip < 25; strip += 4) {
        const int q0 = strip * 16;
        int qr = q0 + l15; if (qr > NTOK - 1) qr = NTOK - 1;  // clamp pad rows
        const f16x8 qf = *(const f16x8*)(qb + qr * 32 + g * 8);  // B: qrow=l15

        // row code for bias/mask (from clamped row; pad rows never stored)
        const int td = qr / 49, rr2 = qr - td * 49, th = rr2 / 7, tw = rr2 - th * 7;
        const int rowc = td * 169 + th * 13 + tw + 1267;
        const int rreg = ((td < 4) ? 4 : 0) | ((th < 4) ? 2 : 0) | ((tw < 4) ? 1 : 0);

        float m = -1e30f, s = 0.f;       // A-frag layout: row = l15
        f32x4 oacc[2] = {z4, z4};        // C/D layout: row = g*4+j

        #pragma unroll
        for (int t = 0; t < 25; t++) {
            // S^T tile: A = K-tile, B = Q -> lane holds (qrow=l15, ktok=g*4+j)
            const f16x8 kf = *(const f16x8*)&k_lds[t * 512 + lane * 8];
            f32x4 sv = MFMA_K32(kf, qf, z4);

            // + rel-pos bias + shift mask, from LDS
            const u16x4 cc4 = *(const u16x4*)&cc_lds[t * 16 + g * 4];
            #pragma unroll
            for (int j = 0; j < 4; j++) {
                const int cw = (int)cc4[j];
                float b = (float)tbl_lds[rowc - (cw & 0xFFF)];
                if (((rreg ^ (cw >> 12)) & wtype) != 0) b += MASKF;
                sv[j] += b;
            }
            if (t == 24 && g >= 2) {  // pad cols 392..399
                #pragma unroll
                for (int j = 0; j < 4; j++) sv[j] = -1e30f;
            }

            // full-row max (row = l15 across the 4 lane-groups)
            float fm = fmaxf(fmaxf(sv[0], sv[1]), fmaxf(sv[2], sv[3]));
            fm = fmaxf(fm, __shfl_xor(fm, 16));
            fm = fmaxf(fm, __shfl_xor(fm, 32));
            if (__any(fm > m)) {      // wave-uniform; exact when skipped
                const float nm = fmaxf(m, fm);
                const float sc = EXP2F(m - nm);   // for row l15
                s *= sc;
                // oacc rows are g*4+j -> rescale with THOSE rows' factors
                #pragma unroll
                for (int j = 0; j < 4; j++) {
                    const float scj = __shfl(sc, g * 4 + j);
                    oacc[0][j] *= scj;
                    oacc[1][j] *= scj;
                }
                m = nm;
            }

            const float p0 = EXP2F(sv[0] - m);
            const float p1 = EXP2F(sv[1] - m);
            const float p2 = EXP2F(sv[2] - m);
            const float p3 = EXP2F(sv[3] - m);
            s += (p0 + p1) + (p2 + p3);
            f16x4 pa = {(f16)p0, (f16)p1, (f16)p2, (f16)p3};

            #pragma unroll
            for (int nt = 0; nt < 2; nt++) {
                const f16x4 vf = *(const f16x4*)&v_lds[(nt * 16 + l15) * 408 + t * 16 + g * 4];
                oacc[nt] = MFMA_K16(pa, vf, oacc[nt]);
            }
        }

        s += __shfl_xor(s, 16);
        s += __shfl_xor(s, 32);
        const float rinv = 1.0f / s;   // for qrow = l15

        // output rows qrow = q0 + g*4 + j; fetch that row's 1/sum from lane g*4+j
        #pragma unroll
        for (int j = 0; j < 4; j++) {
            const float rj = __shfl(rinv, g * 4 + j);
            const int row = q0 + g * 4 + j;
            if (row < NTOK) {
                f16* dst = o_ws + ((size_t)win * NTOK + row) * CDIM + head * 32;
                dst[l15]      = (f16)(oacc[0][j] * rj);
                dst[16 + l15] = (f16)(oacc[1][j] * rj);
            }
        }
    }
}

// ---------------- kernel 3: proj GEMM + window-reverse/roll scatter ----------------
__global__ __launch_bounds__(256, 3) void proj_kernel(
    const f16* __restrict__ o_ws, const f16* __restrict__ wp,
    const float* __restrict__ bp, float* __restrict__ out)
{
    __shared__ __align__(16) f16 a_lds[64 * 256];
    const int tid = threadIdx.x;
    const int bm = blockIdx.x * 64;
    for (int i = tid; i < 64 * 24; i += 256) {
        int row = i / 24, c = i - row * 24;
        f16x8 v = *(const f16x8*)(o_ws + (size_t)(bm + row) * CDIM + c * 8);
        *(f16x8*)&a_lds[row * 256 + ((c ^ (row & 7)) << 3)] = v;
    }
    __syncthreads();

    const int lane = tid & 63, wv = tid >> 6;
    const int l15 = lane & 15, g = lane >> 4;
    const int m0 = (wv & 1) * 32, n0 = (wv >> 1) * 96;

    const f32x4 z4 = {0.f, 0.f, 0.f, 0.f};
    f32x4 acc[2][6];
    #pragma unroll
    for (int mi = 0; mi < 2; mi++)
        #pragma unroll
        for (int ni = 0; ni < 6; ni++) acc[mi][ni] = z4;

    #pragma unroll
    for (int kk = 0; kk < 6; kk++) {
        f16x8 af[2];
        #pragma unroll
        for (int mi = 0; mi < 2; mi++) {
            int row = m0 + mi * 16 + l15;
            af[mi] = *(const f16x8*)&a_lds[row * 256 + (((kk * 4 + g) ^ (row & 7)) << 3)];
        }
        #pragma unroll
        for (int ni = 0; ni < 6; ni++) {
            const f16x8 bf = *(const f16x8*)&wp[(n0 + ni * 16 + l15) * CDIM + kk * 32 + g * 8];
            #pragma unroll
            for (int mi = 0; mi < 2; mi++)
                acc[mi][ni] = MFMA_K32(af[mi], bf, acc[mi][ni]);
        }
    }

    #pragma unroll
    for (int mi = 0; mi < 2; mi++) {
        const int tok0 = bm + m0 + mi * 16 + g * 4;
        #pragma unroll
        for (int j = 0; j < 4; j++) {
            const int tok = tok0 + j;
            const int win = tok / NTOK, nloc = tok - win * NTOK;
            const int td = nloc / 49, r2 = nloc - td * 49, th = r2 / 7, tw = r2 - th * 7;
            const int wd = win >> 6, wh = (win >> 3) & 7, ww = win & 7;
            const int d = (wd * 8 + td + 4) & 15;
            int hh = wh * 7 + th + 3; if (hh >= 56) hh -= 56;
            int wco = ww * 7 + tw + 3; if (wco >= 56) wco -= 56;
            float* dst = out + ((d * 56 + hh) * 56 + wco) * CDIM;
            #pragma unroll
            for (int ni = 0; ni < 6; ni++) {
                const int n = n0 + ni * 16 + l15;
                dst[n] = acc[mi][ni][j] + bp[n];
            }
        }
    }
}

// ---------------- launch ----------------
extern "C" void kernel_launch(void* const* d_in, const int* in_sizes, int n_in,
                              void* d_out, int out_size, void* d_ws, size_t ws_size,
                              hipStream_t stream) {
    const float* x     = (const float*)d_in[0];
    const float* wqkv  = (const float*)d_in[1];
    const float* bqkv  = (const float*)d_in[2];
    const float* wproj = (const float*)d_in[3];
    const float* bproj = (const float*)d_in[4];
    const float* rtbl  = (const float*)d_in[5];
    float* out = (float*)d_out;

    // workspace layout (~77.4 MB)
    const size_t QKV_BYTES = (size_t)NWIN * HEADS * NTOK * 32 * sizeof(f16);  // 19,267,584
    char* ws = (char*)d_ws;
    f16* q_ws   = (f16*)(ws);
    f16* k_ws   = (f16*)(ws + QKV_BYTES);
    f16* v_ws   = (f16*)(ws + 2 * QKV_BYTES);
    f16* o_ws   = (f16*)(ws + 3 * QKV_BYTES);
    f16* tblT   = (f16*)(ws + 4 * QKV_BYTES);                         // 30,420 B
    unsigned short* ccg = (unsigned short*)(ws + 4 * QKV_BYTES + 30424);  // 800 B
    f16* wq_h   = (f16*)(ws + 4 * QKV_BYTES + 30424 + 800);           // 221,184 B
    f16* wp_h   = (f16*)(ws + 4 * QKV_BYTES + 30424 + 800 + 221184);  // 73,728 B

    wconv_kernel<<<432, 256, 0, stream>>>(wqkv, wproj, wq_h, wp_h);
    tab_kernel<<<60, 256, 0, stream>>>(rtbl, tblT, ccg);
    qkv_kernel<<<784, 256, 0, stream>>>(x, wq_h, bqkv, q_ws, k_ws, v_ws);
    attn_kernel<<<768, 256, 0, stream>>>(q_ws, k_ws, v_ws, tblT, ccg, o_ws);
    proj_kernel<<<784, 256, 0, stream>>>(o_ws, wp_h, bproj, out);
}

// Round 8
// 228.921 us; speedup vs baseline: 2.8238x; 2.8238x over previous
//
#include <hip/hip_runtime.h>

// ShiftedWindowAttention3d on MI355X (gfx950).
// x[1,16,56,56,192], WIN=(8,7,7), SHIFT=(4,3,3) -> no pad, shifted.
// 128 windows x 392 tokens, 6 heads x hd=32.
// Round 8: flash attn with NON-UNROLLED paired tile loop (#pragma unroll 1,
// 12 pairs + tile-24 epilogue) to prevent scheduler hoisting -> register
// spills -> 750MB of scratch HBM traffic (r7 post-mortem). T13 defer-rescale
// (threshold 8). Bias/mask from LDS (5.1KB table + colcode LUT).

typedef _Float16 f16;
typedef __attribute__((ext_vector_type(8))) _Float16 f16x8;
typedef __attribute__((ext_vector_type(4))) _Float16 f16x4;
typedef __attribute__((ext_vector_type(4))) float f32x4;
typedef __attribute__((ext_vector_type(4))) unsigned short u16x4;

#define MFMA_K32(a, b, c) __builtin_amdgcn_mfma_f32_16x16x32_f16((a), (b), (c), 0, 0, 0)
#define MFMA_K16(a, b, c) __builtin_amdgcn_mfma_f32_16x16x16f16((a), (b), (c), 0, 0, 0)
#define EXP2F(x) __builtin_amdgcn_exp2f(x)

#define HEADS 6
#define NWIN 128
#define NTOK 392
#define CDIM 192
#define TBLN 2535                    // 15*13*13
#define LOG2E 1.4426950408889634f
#define QSCALE 0.2550868562622215f    // hd^-0.5 * log2e
#define MASKF (-144.26950408889634f)  // -100 * log2e
#define VSTRIDE 392

__device__ inline f16x8 f16x8_zero() {
    f16x8 v = {(f16)0.f,(f16)0.f,(f16)0.f,(f16)0.f,(f16)0.f,(f16)0.f,(f16)0.f,(f16)0.f};
    return v;
}

// ---------------- kernel 0a: weights fp32 -> f16 (q rows pre-scaled) ----------------
__global__ __launch_bounds__(256) void wconv_kernel(
    const float* __restrict__ wqkv, const float* __restrict__ wproj,
    f16* __restrict__ wqkv_h, f16* __restrict__ wproj_h)
{
    int i = blockIdx.x * 256 + threadIdx.x;
    if (i < 576 * 192) {
        float s = (i < 192 * 192) ? QSCALE : 1.0f;
        wqkv_h[i] = (f16)(wqkv[i] * s);
    }
    if (i < 192 * 192) wproj_h[i] = (f16)wproj[i];
}

// ---------------- kernel 0b: per-head bias table transpose + colcode LUT ----------------
__global__ __launch_bounds__(256) void tab_kernel(
    const float* __restrict__ tbl, f16* __restrict__ tblT,
    unsigned short* __restrict__ ccg)
{
    int i = blockIdx.x * 256 + threadIdx.x;
    if (i < HEADS * TBLN) {
        int h = i / TBLN, r = i - h * TBLN;
        tblT[i] = (f16)(tbl[r * 6 + h] * LOG2E);
    }
    if (i < 400) {
        unsigned short v = 0;
        if (i < NTOK) {
            int md = i / 49, m2 = i - md * 49, mh = m2 / 7, mw = m2 - mh * 7;
            int cc = md * 169 + mh * 13 + mw;
            int creg = ((md < 4) ? 4 : 0) | ((mh < 4) ? 2 : 0) | ((mw < 4) ? 1 : 0);
            v = (unsigned short)(cc | (creg << 12));
        }
        ccg[i] = v;
    }
}

// ---------------- kernel 1: gather(roll+window) + QKV GEMM ----------------
__global__ __launch_bounds__(256, 3) void qkv_kernel(
    const float* __restrict__ x, const f16* __restrict__ wq,
    const float* __restrict__ bq,
    f16* __restrict__ q_ws, f16* __restrict__ k_ws, f16* __restrict__ v_ws)
{
    __shared__ __align__(16) f16 a_lds[64 * 256];  // 32 KB, swizzled
    const int tid = threadIdx.x;
    const int bm = blockIdx.x * 64;

    for (int i = tid; i < 64 * 24; i += 256) {
        int row = i / 24, c = i - row * 24;
        int tok = bm + row;
        int win = tok / NTOK, nloc = tok - win * NTOK;
        int td = nloc / 49, r2 = nloc - td * 49, th = r2 / 7, tw = r2 - th * 7;
        int wd = win >> 6, wh = (win >> 3) & 7, ww = win & 7;
        int d = (wd * 8 + td + 4) & 15;
        int hh = wh * 7 + th + 3; if (hh >= 56) hh -= 56;
        int wco = ww * 7 + tw + 3; if (wco >= 56) wco -= 56;
        const float* src = x + ((d * 56 + hh) * 56 + wco) * CDIM + c * 8;
        const float4 u0 = *(const float4*)(src);
        const float4 u1 = *(const float4*)(src + 4);
        f16x8 v;
        v[0] = (f16)u0.x; v[1] = (f16)u0.y; v[2] = (f16)u0.z; v[3] = (f16)u0.w;
        v[4] = (f16)u1.x; v[5] = (f16)u1.y; v[6] = (f16)u1.z; v[7] = (f16)u1.w;
        *(f16x8*)&a_lds[row * 256 + ((c ^ (row & 7)) << 3)] = v;
    }
    __syncthreads();

    const int lane = tid & 63, wv = tid >> 6;
    const int l15 = lane & 15, g = lane >> 4;
    const int m0 = (wv & 1) * 32, nq = wv >> 1;
    const f32x4 z4 = {0.f, 0.f, 0.f, 0.f};

    for (int half = 0; half < 2; half++) {
        const int n0 = half * 288 + nq * 144;
        f32x4 acc[2][9];
        #pragma unroll
        for (int mi = 0; mi < 2; mi++)
            #pragma unroll
            for (int ni = 0; ni < 9; ni++) acc[mi][ni] = z4;

        #pragma unroll
        for (int kk = 0; kk < 6; kk++) {
            f16x8 af[2];
            #pragma unroll
            for (int mi = 0; mi < 2; mi++) {
                int row = m0 + mi * 16 + l15;
                af[mi] = *(const f16x8*)&a_lds[row * 256 + (((kk * 4 + g) ^ (row & 7)) << 3)];
            }
            #pragma unroll
            for (int ni = 0; ni < 9; ni++) {
                const f16x8 bf = *(const f16x8*)&wq[(n0 + ni * 16 + l15) * CDIM + kk * 32 + g * 8];
                #pragma unroll
                for (int mi = 0; mi < 2; mi++)
                    acc[mi][ni] = MFMA_K32(af[mi], bf, acc[mi][ni]);
            }
        }

        #pragma unroll
        for (int mi = 0; mi < 2; mi++) {
            const int tok0 = bm + m0 + mi * 16 + g * 4;
            const int win = tok0 / NTOK, nloc0 = tok0 - win * NTOK;
            #pragma unroll
            for (int ni = 0; ni < 9; ni++) {
                const int n = n0 + ni * 16 + l15;
                const float bias = bq[n] * ((n < 192) ? QSCALE : 1.0f);
                if (n < 192) {
                    const int head = n >> 5, hd = n & 31;
                    f16* dst = q_ws + ((win * HEADS + head) * NTOK + nloc0) * 32 + hd;
                    #pragma unroll
                    for (int j = 0; j < 4; j++)
                        dst[j * 32] = (f16)(acc[mi][ni][j] + bias);
                } else if (n < 384) {
                    const int cc = n - 192, head = cc >> 5, hd = cc & 31;
                    f16* dst = k_ws + ((win * HEADS + head) * NTOK + nloc0) * 32 + hd;
                    #pragma unroll
                    for (int j = 0; j < 4; j++)
                        dst[j * 32] = (f16)(acc[mi][ni][j] + bias);
                } else {
                    const int cc = n - 384, head = cc >> 5, hd = cc & 31;
                    f16x4 pk;
                    #pragma unroll
                    for (int j = 0; j < 4; j++) pk[j] = (f16)(acc[mi][ni][j] + bias);
                    *(f16x4*)(v_ws + ((win * HEADS + head) * 32 + hd) * NTOK + nloc0) = pk;
                }
            }
        }
    }
}

// ---------------- kernel 2: fused window attention (flash, non-unrolled) ----------------
// grid 768 = 128 win x 6 heads, 256 threads (4 waves), 2 blocks/CU.
__global__ __launch_bounds__(256, 2) void attn_kernel(
    const f16* __restrict__ q_ws, const f16* __restrict__ k_ws,
    const f16* __restrict__ v_ws, const f16* __restrict__ tblT,
    const unsigned short* __restrict__ ccg, f16* __restrict__ o_ws)
{
    __shared__ __align__(16) f16 k_lds[25 * 512];          // frag-major, 25.6 KB
    __shared__ __align__(16) f16 v_lds[32 * VSTRIDE];      // V^T rows, 25.1 KB
    __shared__ __align__(16) f16 tbl_lds[TBLN + 1];        // per-head bias, 5.1 KB
    __shared__ __align__(16) unsigned short cc_lds[400];   // colcode|creg<<12

    const int tid = threadIdx.x;
    const int bid = blockIdx.x;
    const int win = bid / 6, head = bid - win * 6;
    const int wd = win >> 6, wh = (win >> 3) & 7, ww = win & 7;
    const int wtype = ((wd == 1) ? 4 : 0) | ((wh == 7) ? 2 : 0) | ((ww == 7) ? 1 : 0);
    const f16* kb = k_ws + (size_t)(win * HEADS + head) * NTOK * 32;
    const f16* vb = v_ws + (size_t)(win * HEADS + head) * 32 * NTOK;
    const f16* qb = q_ws + (size_t)(win * HEADS + head) * NTOK * 32;

    for (int i = tid; i < 1600; i += 256) {
        const int tok = ((i >> 6) << 4) | (i & 15);
        const int gg = (i >> 4) & 3;
        f16x8 v = f16x8_zero();
        if (tok < NTOK) v = *(const f16x8*)(kb + tok * 32 + gg * 8);
        *(f16x8*)&k_lds[i * 8] = v;
    }
    for (int i = tid; i < 32 * 51; i += 256) {
        const int hd = i / 51, c = i - hd * 51;
        if (c < 49) {
            f16x8 v = *(const f16x8*)(vb + hd * NTOK + c * 8);
            *(f16x8*)&v_lds[hd * VSTRIDE + c * 8] = v;
        }
    }
    for (int i = tid; i < TBLN; i += 256) tbl_lds[i] = tblT[head * TBLN + i];
    for (int i = tid; i < 400; i += 256) cc_lds[i] = ccg[i];
    __syncthreads();

    const int lane = tid & 63, wv = tid >> 6, l15 = lane & 15, g = lane >> 4;
    const f32x4 z4 = {0.f, 0.f, 0.f, 0.f};

    for (int strip = wv; strip < 25; strip += 4) {
        const int q0 = strip * 16;
        int qr = q0 + l15; if (qr > NTOK - 1) qr = NTOK - 1;
        const f16x8 qf = *(const f16x8*)(qb + qr * 32 + g * 8);  // B: qrow=l15

        const int td = qr / 49, rr2 = qr - td * 49, th = rr2 / 7, tw = rr2 - th * 7;
        const int rowc = td * 169 + th * 13 + tw + 1267;
        const int rreg = ((td < 4) ? 4 : 0) | ((th < 4) ? 2 : 0) | ((tw < 4) ? 1 : 0);

        float m = -1e30f, s = 0.f;       // A-frag layout: row = l15
        f32x4 oacc[2] = {z4, z4};        // C/D layout: row = g*4+j

        #pragma unroll 1
        for (int it = 0; it < 12; ++it) {
            const int t0 = it * 2;
            const f16x8 kf0 = *(const f16x8*)&k_lds[t0 * 512 + lane * 8];
            const f16x8 kf1 = *(const f16x8*)&k_lds[(t0 + 1) * 512 + lane * 8];
            f32x4 sv0 = MFMA_K32(kf0, qf, z4);
            f32x4 sv1 = MFMA_K32(kf1, qf, z4);

            const u16x4 cc0 = *(const u16x4*)&cc_lds[t0 * 16 + g * 4];
            const u16x4 cc1 = *(const u16x4*)&cc_lds[(t0 + 1) * 16 + g * 4];
            #pragma unroll
            for (int j = 0; j < 4; j++) {
                const int cw0 = (int)cc0[j], cw1 = (int)cc1[j];
                float b0 = (float)tbl_lds[rowc - (cw0 & 0xFFF)];
                float b1 = (float)tbl_lds[rowc - (cw1 & 0xFFF)];
                if (((rreg ^ (cw0 >> 12)) & wtype) != 0) b0 += MASKF;
                if (((rreg ^ (cw1 >> 12)) & wtype) != 0) b1 += MASKF;
                sv0[j] += b0;
                sv1[j] += b1;
            }

            float fm = fmaxf(fmaxf(fmaxf(sv0[0], sv0[1]), fmaxf(sv0[2], sv0[3])),
                             fmaxf(fmaxf(sv1[0], sv1[1]), fmaxf(sv1[2], sv1[3])));
            fm = fmaxf(fm, __shfl_xor(fm, 16));
            fm = fmaxf(fm, __shfl_xor(fm, 32));
            if (__any(fm > m + 8.f)) {       // T13 defer: P bounded by 2^8
                const float nm = fmaxf(m, fm);
                const float sc = EXP2F(m - nm);   // row l15's factor
                s *= sc;
                #pragma unroll
                for (int j = 0; j < 4; j++) {
                    const float scj = __shfl(sc, g * 4 + j);  // row g*4+j's factor
                    oacc[0][j] *= scj;
                    oacc[1][j] *= scj;
                }
                m = nm;
            }

            f16x4 pa0, pa1;
            #pragma unroll
            for (int j = 0; j < 4; j++) {
                const float p0 = EXP2F(sv0[j] - m);
                const float p1 = EXP2F(sv1[j] - m);
                s += p0 + p1;
                pa0[j] = (f16)p0;
                pa1[j] = (f16)p1;
            }

            #pragma unroll
            for (int nt = 0; nt < 2; nt++) {
                const int vrow = (nt * 16 + l15) * VSTRIDE + g * 4;
                const f16x4 vf0 = *(const f16x4*)&v_lds[vrow + t0 * 16];
                const f16x4 vf1 = *(const f16x4*)&v_lds[vrow + (t0 + 1) * 16];
                oacc[nt] = MFMA_K16(pa0, vf0, oacc[nt]);
                oacc[nt] = MFMA_K16(pa1, vf1, oacc[nt]);
            }
        }

        // epilogue tile 24 (contains pad cols 392..399 at g>=2)
        {
            const f16x8 kf = *(const f16x8*)&k_lds[24 * 512 + lane * 8];
            f32x4 sv = MFMA_K32(kf, qf, z4);
            const u16x4 cc4 = *(const u16x4*)&cc_lds[24 * 16 + g * 4];
            #pragma unroll
            for (int j = 0; j < 4; j++) {
                const int cw = (int)cc4[j];
                float b = (float)tbl_lds[rowc - (cw & 0xFFF)];
                if (((rreg ^ (cw >> 12)) & wtype) != 0) b += MASKF;
                sv[j] = (g >= 2) ? -1e30f : (sv[j] + b);
            }
            float fm = fmaxf(fmaxf(sv[0], sv[1]), fmaxf(sv[2], sv[3]));
            fm = fmaxf(fm, __shfl_xor(fm, 16));
            fm = fmaxf(fm, __shfl_xor(fm, 32));
            if (__any(fm > m + 8.f)) {
                const float nm = fmaxf(m, fm);
                const float sc = EXP2F(m - nm);
                s *= sc;
                #pragma unroll
                for (int j = 0; j < 4; j++) {
                    const float scj = __shfl(sc, g * 4 + j);
                    oacc[0][j] *= scj;
                    oacc[1][j] *= scj;
                }
                m = nm;
            }
            f16x4 pa;
            #pragma unroll
            for (int j = 0; j < 4; j++) {
                const float p = EXP2F(sv[j] - m);
                s += p;
                pa[j] = (f16)p;
            }
            #pragma unroll
            for (int nt = 0; nt < 2; nt++) {
                const f16x4 vf = *(const f16x4*)&v_lds[(nt * 16 + l15) * VSTRIDE + 24 * 16 + g * 4];
                oacc[nt] = MFMA_K16(pa, vf, oacc[nt]);
            }
        }

        s += __shfl_xor(s, 16);
        s += __shfl_xor(s, 32);
        const float rinv = 1.0f / s;   // for qrow = l15

        #pragma unroll
        for (int j = 0; j < 4; j++) {
            const float rj = __shfl(rinv, g * 4 + j);
            const int row = q0 + g * 4 + j;
            if (row < NTOK) {
                f16* dst = o_ws + ((size_t)win * NTOK + row) * CDIM + head * 32;
                dst[l15]      = (f16)(oacc[0][j] * rj);
                dst[16 + l15] = (f16)(oacc[1][j] * rj);
            }
        }
    }
}

// ---------------- kernel 3: proj GEMM + window-reverse/roll scatter ----------------
__global__ __launch_bounds__(256, 3) void proj_kernel(
    const f16* __restrict__ o_ws, const f16* __restrict__ wp,
    const float* __restrict__ bp, float* __restrict__ out)
{
    __shared__ __align__(16) f16 a_lds[64 * 256];
    const int tid = threadIdx.x;
    const int bm = blockIdx.x * 64;
    for (int i = tid; i < 64 * 24; i += 256) {
        int row = i / 24, c = i - row * 24;
        f16x8 v = *(const f16x8*)(o_ws + (size_t)(bm + row) * CDIM + c * 8);
        *(f16x8*)&a_lds[row * 256 + ((c ^ (row & 7)) << 3)] = v;
    }
    __syncthreads();

    const int lane = tid & 63, wv = tid >> 6;
    const int l15 = lane & 15, g = lane >> 4;
    const int m0 = (wv & 1) * 32, n0 = (wv >> 1) * 96;

    const f32x4 z4 = {0.f, 0.f, 0.f, 0.f};
    f32x4 acc[2][6];
    #pragma unroll
    for (int mi = 0; mi < 2; mi++)
        #pragma unroll
        for (int ni = 0; ni < 6; ni++) acc[mi][ni] = z4;

    #pragma unroll
    for (int kk = 0; kk < 6; kk++) {
        f16x8 af[2];
        #pragma unroll
        for (int mi = 0; mi < 2; mi++) {
            int row = m0 + mi * 16 + l15;
            af[mi] = *(const f16x8*)&a_lds[row * 256 + (((kk * 4 + g) ^ (row & 7)) << 3)];
        }
        #pragma unroll
        for (int ni = 0; ni < 6; ni++) {
            const f16x8 bf = *(const f16x8*)&wp[(n0 + ni * 16 + l15) * CDIM + kk * 32 + g * 8];
            #pragma unroll
            for (int mi = 0; mi < 2; mi++)
                acc[mi][ni] = MFMA_K32(af[mi], bf, acc[mi][ni]);
        }
    }

    #pragma unroll
    for (int mi = 0; mi < 2; mi++) {
        const int tok0 = bm + m0 + mi * 16 + g * 4;
        #pragma unroll
        for (int j = 0; j < 4; j++) {
            const int tok = tok0 + j;
            const int win = tok / NTOK, nloc = tok - win * NTOK;
            const int td = nloc / 49, r2 = nloc - td * 49, th = r2 / 7, tw = r2 - th * 7;
            const int wd = win >> 6, wh = (win >> 3) & 7, ww = win & 7;
            const int d = (wd * 8 + td + 4) & 15;
            int hh = wh * 7 + th + 3; if (hh >= 56) hh -= 56;
            int wco = ww * 7 + tw + 3; if (wco >= 56) wco -= 56;
            float* dst = out + ((d * 56 + hh) * 56 + wco) * CDIM;
            #pragma unroll
            for (int ni = 0; ni < 6; ni++) {
                const int n = n0 + ni * 16 + l15;
                dst[n] = acc[mi][ni][j] + bp[n];
            }
        }
    }
}

// ---------------- launch ----------------
extern "C" void kernel_launch(void* const* d_in, const int* in_sizes, int n_in,
                              void* d_out, int out_size, void* d_ws, size_t ws_size,
                              hipStream_t stream) {
    const float* x     = (const float*)d_in[0];
    const float* wqkv  = (const float*)d_in[1];
    const float* bqkv  = (const float*)d_in[2];
    const float* wproj = (const float*)d_in[3];
    const float* bproj = (const float*)d_in[4];
    const float* rtbl  = (const float*)d_in[5];
    float* out = (float*)d_out;

    const size_t QKV_BYTES = (size_t)NWIN * HEADS * NTOK * 32 * sizeof(f16);  // 19,267,584
    char* ws = (char*)d_ws;
    f16* q_ws   = (f16*)(ws);
    f16* k_ws   = (f16*)(ws + QKV_BYTES);
    f16* v_ws   = (f16*)(ws + 2 * QKV_BYTES);
    f16* o_ws   = (f16*)(ws + 3 * QKV_BYTES);
    f16* tblT   = (f16*)(ws + 4 * QKV_BYTES);                         // 30,420 B
    unsigned short* ccg = (unsigned short*)(ws + 4 * QKV_BYTES + 30424);  // 800 B
    f16* wq_h   = (f16*)(ws + 4 * QKV_BYTES + 30424 + 800);           // 221,184 B
    f16* wp_h   = (f16*)(ws + 4 * QKV_BYTES + 30424 + 800 + 221184);  // 73,728 B

    wconv_kernel<<<432, 256, 0, stream>>>(wqkv, wproj, wq_h, wp_h);
    tab_kernel<<<60, 256, 0, stream>>>(rtbl, tblT, ccg);
    qkv_kernel<<<784, 256, 0, stream>>>(x, wq_h, bqkv, q_ws, k_ws, v_ws);
    attn_kernel<<<768, 256, 0, stream>>>(q_ws, k_ws, v_ws, tblT, ccg, o_ws);
    proj_kernel<<<784, 256, 0, stream>>>(o_ws, wp_h, bproj, out);
}